// Round 4
// baseline (51.093 us; speedup 1.0000x reference)
//
#include <hip/hip_runtime.h>
#include <hip/hip_bf16.h>

#define B_ 8
#define L_ 2048
#define D_ 256

typedef __bf16 bf16x8 __attribute__((ext_vector_type(8)));
typedef float f32x4 __attribute__((ext_vector_type(4)));

// round-to-nearest-even f32 -> bf16 (finite inputs)
static __device__ __forceinline__ unsigned short f2bf(float f) {
    unsigned int u = __builtin_bit_cast(unsigned int, f);
    unsigned int lsb = (u >> 16) & 1u;
    u += 0x7fffu + lsb;
    return (unsigned short)(u >> 16);
}

static __device__ __forceinline__ void gload_lds16(const void* g, void* l) {
    __builtin_amdgcn_global_load_lds(
        (const __attribute__((address_space(1))) unsigned int*)g,
        (__attribute__((address_space(3))) unsigned int*)l, 16, 0, 0);
}

// ---------------- prep: A = bf16(c*cqw), Q = bf16(q), s0 = c.cw + bias, s1 = c.qw
__global__ __launch_bounds__(256) void prep_kernel(
    const float* __restrict__ c, const float* __restrict__ q,
    const float* __restrict__ cw, const float* __restrict__ qw,
    const float* __restrict__ cqw, const float* __restrict__ bias,
    unsigned short* __restrict__ Abf, unsigned short* __restrict__ Qbf,
    float* __restrict__ s0, float* __restrict__ s1)
{
    const int wave = threadIdx.x >> 6;
    const int lane = threadIdx.x & 63;
    const int row  = blockIdx.x * 4 + wave;          // 0 .. B*L-1

    const float4 cv  = *(const float4*)(c   + (size_t)row * D_ + lane * 4);
    const float4 qv  = *(const float4*)(q   + (size_t)row * D_ + lane * 4);
    const float4 wc  = *(const float4*)(cw  + lane * 4);
    const float4 wq  = *(const float4*)(qw  + lane * 4);
    const float4 wcq = *(const float4*)(cqw + lane * 4);

    ushort4 av, qb;
    av.x = f2bf(cv.x * wcq.x); av.y = f2bf(cv.y * wcq.y);
    av.z = f2bf(cv.z * wcq.z); av.w = f2bf(cv.w * wcq.w);
    qb.x = f2bf(qv.x); qb.y = f2bf(qv.y);
    qb.z = f2bf(qv.z); qb.w = f2bf(qv.w);
    *(ushort4*)(Abf + (size_t)row * D_ + lane * 4) = av;
    *(ushort4*)(Qbf + (size_t)row * D_ + lane * 4) = qb;

    float p0 = cv.x * wc.x + cv.y * wc.y + cv.z * wc.z + cv.w * wc.w;
    float p1 = cv.x * wq.x + cv.y * wq.y + cv.z * wq.z + cv.w * wq.w;
    #pragma unroll
    for (int off = 32; off > 0; off >>= 1) {
        p0 += __shfl_down(p0, off);
        p1 += __shfl_down(p1, off);
    }
    if (lane == 0) { s0[row] = p0 + bias[0]; s1[row] = p1; }
}

// ---------------- GEMM: out[b,i,j] = s0[i]+s1[j] + sum_k A[i,k]*Q[j,k] -------
// 128x128 tile, BK=32. Each block does 4 col-adjacent tiles via one flattened
// 32-step pipeline (3 LDS buffers, counted vmcnt, never drains). Stores of
// tile t are interleaved 8-per-step into tile t+1's K-loop so the HBM write
// stream runs continuously. s0/s1 folded into accumulator init.
#define BM 128
#define BN 128
#define BK 32

__global__ __launch_bounds__(256, 2) void gemm_kernel(
    const unsigned short* __restrict__ A, const unsigned short* __restrict__ Q,
    const float* __restrict__ s0, const float* __restrict__ s1,
    float* __restrict__ out)
{
    __shared__ __align__(16) unsigned short As[3][BM * BK];   // 3 x 8 KiB
    __shared__ __align__(16) unsigned short Qs[3][BM * BK];   // 3 x 8 KiB

    const int tid  = threadIdx.x;
    const int wave = tid >> 6;
    const int lane = tid & 63;

    // 512 blocks; XCD swizzle: batch k -> XCD k; each block = 4 col tiles
    const int beta = blockIdx.x;                       // 0..511
    const int bs   = ((beta & 7) << 6) | (beta >> 3);  // bijective
    const int b    = bs >> 6;        // 0..7
    const int rpnl = (bs >> 2) & 15; // row panel 0..15
    const int cg   = bs & 3;         // col group 0..3
    const int brow  = rpnl * BM;
    const int bcol0 = cg * 4 * BN;

    const unsigned short* Ab = A + ((size_t)b * L_ + brow) * D_;
    const unsigned short* Qb = Q + ((size_t)b * L_ + bcol0) * D_;
    float* outp = out + ((size_t)b * L_ + brow) * L_ + bcol0;

    const int wr = wave >> 1;   // 0..1
    const int wc = wave & 1;    // 0..1

    // preload scalar row/col terms (once; no mid-loop VMEM loads)
    float s0v[4][4];   // [m][r]
    #pragma unroll
    for (int m = 0; m < 4; ++m)
        #pragma unroll
        for (int r = 0; r < 4; ++r)
            s0v[m][r] = s0[(size_t)b * L_ + brow + wr * 64 + m * 16 + (lane >> 4) * 4 + r];
    float s1v[4][4];   // [tile][n]
    #pragma unroll
    for (int t = 0; t < 4; ++t)
        #pragma unroll
        for (int n = 0; n < 4; ++n)
            s1v[t][n] = s1[(size_t)b * L_ + bcol0 + t * BN + wc * 64 + n * 16 + (lane & 15)];

    f32x4 acc[4][4], st[4][4];
    #pragma unroll
    for (int m = 0; m < 4; ++m)
        #pragma unroll
        for (int n = 0; n < 4; ++n)
            #pragma unroll
            for (int r = 0; r < 4; ++r)
                acc[m][n][r] = s0v[m][r] + s1v[0][n];   // tile-0 init

#define STAGE(G) do {                                                        \
        const int k0_ = ((G) & 7) * BK;                                      \
        const size_t qo_ = (size_t)((G) >> 3) * BN * D_;                     \
        unsigned short* ab_ = &As[(G) % 3][0];                               \
        unsigned short* qb_ = &Qs[(G) % 3][0];                               \
        _Pragma("unroll")                                                    \
        for (int i_ = 0; i_ < 2; ++i_) {                                     \
            const int sidx_ = i_ * 256 + wave * 64 + lane;                   \
            const int row_  = sidx_ >> 2;                                    \
            const int sl_   = sidx_ & 3;                                     \
            const int ks_   = k0_ + ((sl_ ^ ((row_ >> 1) & 3)) << 3);        \
            const int wb_   = (i_ * 256 + wave * 64) * 8;                    \
            gload_lds16(Ab + (size_t)row_ * D_ + ks_, ab_ + wb_);            \
            gload_lds16(Qb + qo_ + (size_t)row_ * D_ + ks_, qb_ + wb_);      \
        }                                                                    \
    } while (0)

#define COMPUTE(G) do {                                                      \
        const unsigned short* ab_ = &As[(G) % 3][0];                         \
        const unsigned short* qb_ = &Qs[(G) % 3][0];                         \
        bf16x8 af_[4], qf_[4];                                               \
        _Pragma("unroll")                                                    \
        for (int m_ = 0; m_ < 4; ++m_) {                                     \
            const int row_ = wr * 64 + m_ * 16 + (lane & 15);                \
            const int idx_ = row_ * 32 + (((lane >> 4) ^ ((row_ >> 1) & 3)) << 3); \
            af_[m_] = *(const bf16x8*)(ab_ + idx_);                          \
        }                                                                    \
        _Pragma("unroll")                                                    \
        for (int n_ = 0; n_ < 4; ++n_) {                                     \
            const int row_ = wc * 64 + n_ * 16 + (lane & 15);                \
            const int idx_ = row_ * 32 + (((lane >> 4) ^ ((row_ >> 1) & 3)) << 3); \
            qf_[n_] = *(const bf16x8*)(qb_ + idx_);                          \
        }                                                                    \
        __builtin_amdgcn_s_setprio(1);                                       \
        _Pragma("unroll")                                                    \
        for (int m_ = 0; m_ < 4; ++m_)                                       \
            _Pragma("unroll")                                                \
            for (int n_ = 0; n_ < 4; ++n_)                                   \
                acc[m_][n_] = __builtin_amdgcn_mfma_f32_16x16x32_bf16(       \
                    af_[m_], qf_[n_], acc[m_][n_], 0, 0, 0);                 \
        __builtin_amdgcn_s_setprio(0);                                       \
    } while (0)

#define SLICE(G) do { if ((G) >= 8) {                                        \
        const int t_ = ((G) >> 3) - 1, s_ = (G) & 7, m_ = s_ >> 1;           \
        _Pragma("unroll")                                                    \
        for (int rr_ = 0; rr_ < 2; ++rr_) {                                  \
            const int r_   = (s_ & 1) * 2 + rr_;                             \
            const int row_ = wr * 64 + m_ * 16 + (lane >> 4) * 4 + r_;       \
            float* rp_ = outp + (size_t)t_ * BN + (size_t)row_ * L_;         \
            _Pragma("unroll")                                                \
            for (int n_ = 0; n_ < 4; ++n_)                                   \
                rp_[wc * 64 + n_ * 16 + (lane & 15)] = st[m_][n_][r_];       \
        } } } while (0)

#define BOUNDARY(G) do { if (((G) & 7) == 7 && (G) < 31) {                   \
        const int tn_ = ((G) >> 3) + 1;                                      \
        _Pragma("unroll")                                                    \
        for (int m_ = 0; m_ < 4; ++m_)                                       \
            _Pragma("unroll")                                                \
            for (int n_ = 0; n_ < 4; ++n_) {                                 \
                st[m_][n_] = acc[m_][n_];                                    \
                _Pragma("unroll")                                            \
                for (int r_ = 0; r_ < 4; ++r_)                               \
                    acc[m_][n_][r_] = s0v[m_][r_] + s1v[tn_][n_];            \
            }                                                                \
    } } while (0)

#define STEP(G, VM) do {                                                     \
        if ((G) + 2 < 32) STAGE((G) + 2);                                    \
        SLICE(G);                                                            \
        asm volatile("s_waitcnt vmcnt(" #VM ")" ::: "memory");               \
        __builtin_amdgcn_s_barrier();                                        \
        COMPUTE(G);                                                          \
        asm volatile("" ::: "memory");                                       \
        __builtin_amdgcn_s_barrier();                                        \
        BOUNDARY(G);                                                         \
    } while (0)

    STAGE(0); STAGE(1);

    STEP(0, 8);   STEP(1, 8);   STEP(2, 8);   STEP(3, 8);
    STEP(4, 8);   STEP(5, 8);   STEP(6, 8);   STEP(7, 8);
    STEP(8, 16);  STEP(9, 24);
    STEP(10, 32); STEP(11, 32); STEP(12, 32); STEP(13, 32);
    STEP(14, 32); STEP(15, 32); STEP(16, 32); STEP(17, 32);
    STEP(18, 32); STEP(19, 32); STEP(20, 32); STEP(21, 32);
    STEP(22, 32); STEP(23, 32); STEP(24, 32); STEP(25, 32);
    STEP(26, 32); STEP(27, 32); STEP(28, 32); STEP(29, 32);
    STEP(30, 28); STEP(31, 24);

#undef STEP
#undef BOUNDARY
#undef SLICE
#undef COMPUTE
#undef STAGE

    // tail: store tile 3 straight from acc
    #pragma unroll
    for (int m = 0; m < 4; ++m)
        #pragma unroll
        for (int r = 0; r < 4; ++r) {
            const int row = wr * 64 + m * 16 + (lane >> 4) * 4 + r;
            float* rp = outp + (size_t)3 * BN + (size_t)row * L_;
            #pragma unroll
            for (int n = 0; n < 4; ++n)
                rp[wc * 64 + n * 16 + (lane & 15)] = acc[m][n][r];
        }
}

// ---------------- fallback (workspace too small): naive, correct, slow ------
__global__ void naive_kernel(const float* __restrict__ c, const float* __restrict__ q,
                             const float* __restrict__ cw, const float* __restrict__ qw,
                             const float* __restrict__ cqw, const float* __restrict__ bias,
                             float* __restrict__ out)
{
    const size_t total = (size_t)B_ * L_ * L_;
    for (size_t idx = (size_t)blockIdx.x * blockDim.x + threadIdx.x; idx < total;
         idx += (size_t)gridDim.x * blockDim.x) {
        const int b = (int)(idx / ((size_t)L_ * L_));
        const int rem = (int)(idx % ((size_t)L_ * L_));
        const int i = rem / L_, j = rem % L_;
        const float* ci = c + ((size_t)b * L_ + i) * D_;
        const float* cj = c + ((size_t)b * L_ + j) * D_;
        const float* qj = q + ((size_t)b * L_ + j) * D_;
        float acc = bias[0];
        for (int d = 0; d < D_; ++d)
            acc += ci[d] * cw[d] + cj[d] * qw[d] + ci[d] * cqw[d] * qj[d];
        out[idx] = acc;
    }
}

extern "C" void kernel_launch(void* const* d_in, const int* in_sizes, int n_in,
                              void* d_out, int out_size, void* d_ws, size_t ws_size,
                              hipStream_t stream) {
    const float* c    = (const float*)d_in[0];
    const float* q    = (const float*)d_in[1];
    const float* cw   = (const float*)d_in[2];
    const float* qw   = (const float*)d_in[3];
    const float* cqw  = (const float*)d_in[4];
    const float* bias = (const float*)d_in[5];
    float* out = (float*)d_out;

    const size_t bytesA = (size_t)B_ * L_ * D_ * 2;            // 8 MiB
    const size_t need   = 2 * bytesA + 2 * (size_t)B_ * L_ * 4; // ~16.1 MiB

    if (ws_size >= need) {
        unsigned short* Abf = (unsigned short*)d_ws;
        unsigned short* Qbf = (unsigned short*)((char*)d_ws + bytesA);
        float* s0 = (float*)((char*)d_ws + 2 * bytesA);
        float* s1 = s0 + (size_t)B_ * L_;
        prep_kernel<<<B_ * L_ / 4, 256, 0, stream>>>(c, q, cw, qw, cqw, bias,
                                                     Abf, Qbf, s0, s1);
        gemm_kernel<<<dim3(512), 256, 0, stream>>>(Abf, Qbf, s0, s1, out);
    } else {
        naive_kernel<<<2048, 256, 0, stream>>>(c, q, cw, qw, cqw, bias, out);
    }
}

// Round 5
// 49.017 us; speedup vs baseline: 1.0424x; 1.0424x over previous
//
#include <hip/hip_runtime.h>
#include <hip/hip_bf16.h>

#define B_ 8
#define L_ 2048
#define D_ 256

typedef __bf16 bf16x8 __attribute__((ext_vector_type(8)));
typedef float f32x4 __attribute__((ext_vector_type(4)));

// round-to-nearest-even f32 -> bf16 (finite inputs)
static __device__ __forceinline__ unsigned short f2bf(float f) {
    unsigned int u = __builtin_bit_cast(unsigned int, f);
    unsigned int lsb = (u >> 16) & 1u;
    u += 0x7fffu + lsb;
    return (unsigned short)(u >> 16);
}

static __device__ __forceinline__ void gload_lds16(const void* g, void* l) {
    __builtin_amdgcn_global_load_lds(
        (const __attribute__((address_space(1))) unsigned int*)g,
        (__attribute__((address_space(3))) unsigned int*)l, 16, 0, 0);
}

// ---------------- prep: A = bf16(c*cqw), Q = bf16(q), s0 = c.cw + bias, s1 = c.qw
__global__ __launch_bounds__(256) void prep_kernel(
    const float* __restrict__ c, const float* __restrict__ q,
    const float* __restrict__ cw, const float* __restrict__ qw,
    const float* __restrict__ cqw, const float* __restrict__ bias,
    unsigned short* __restrict__ Abf, unsigned short* __restrict__ Qbf,
    float* __restrict__ s0, float* __restrict__ s1)
{
    const int wave = threadIdx.x >> 6;
    const int lane = threadIdx.x & 63;
    const int row  = blockIdx.x * 4 + wave;          // 0 .. B*L-1

    const float4 cv  = *(const float4*)(c   + (size_t)row * D_ + lane * 4);
    const float4 qv  = *(const float4*)(q   + (size_t)row * D_ + lane * 4);
    const float4 wc  = *(const float4*)(cw  + lane * 4);
    const float4 wq  = *(const float4*)(qw  + lane * 4);
    const float4 wcq = *(const float4*)(cqw + lane * 4);

    ushort4 av, qb;
    av.x = f2bf(cv.x * wcq.x); av.y = f2bf(cv.y * wcq.y);
    av.z = f2bf(cv.z * wcq.z); av.w = f2bf(cv.w * wcq.w);
    qb.x = f2bf(qv.x); qb.y = f2bf(qv.y);
    qb.z = f2bf(qv.z); qb.w = f2bf(qv.w);
    *(ushort4*)(Abf + (size_t)row * D_ + lane * 4) = av;
    *(ushort4*)(Qbf + (size_t)row * D_ + lane * 4) = qb;

    float p0 = cv.x * wc.x + cv.y * wc.y + cv.z * wc.z + cv.w * wc.w;
    float p1 = cv.x * wq.x + cv.y * wq.y + cv.z * wq.z + cv.w * wq.w;
    #pragma unroll
    for (int off = 32; off > 0; off >>= 1) {
        p0 += __shfl_down(p0, off);
        p1 += __shfl_down(p1, off);
    }
    if (lane == 0) { s0[row] = p0 + bias[0]; s1[row] = p1; }
}

// ---------------- GEMM: out[b,i,j] = s0[i]+s1[j] + sum_k A[i,k]*Q[j,k] -------
// 256x256 tile (halves L2/L3 panel re-reads vs 128x128), 8 waves (2M x 4N),
// BK=32, 3-deep LDS pipeline with counted vmcnt (R3 structure, proven).
#define BM 256
#define BN 256
#define BK 32
#define NSTEP (D_ / BK)   // 8

__global__ __launch_bounds__(512, 2) void gemm_kernel(
    const unsigned short* __restrict__ A, const unsigned short* __restrict__ Q,
    const float* __restrict__ s0, const float* __restrict__ s1,
    float* __restrict__ out)
{
    // 3 buffers x (A 16KB + Q 16KB) = 96 KiB
    __shared__ __align__(16) unsigned short As[3][BM * BK];
    __shared__ __align__(16) unsigned short Qs[3][BM * BK];

    const int tid  = threadIdx.x;
    const int wave = tid >> 6;
    const int lane = tid & 63;

    // 512 tiles: 8 batches x 8 row x 8 col.  XCD swizzle: batch k -> XCD k.
    const int beta = blockIdx.x;                       // 0..511
    const int bs   = ((beta & 7) << 6) | (beta >> 3);  // bijective
    const int b    = bs >> 6;          // 0..7
    const int brow = ((bs >> 3) & 7) * BM;
    const int bcol = (bs & 7) * BN;

    const unsigned short* Ab = A + ((size_t)b * L_ + brow) * D_;
    const unsigned short* Qb = Q + ((size_t)b * L_ + bcol) * D_;

    const int wr = wave >> 2;   // 0..1  (M half)
    const int wc = wave & 3;    // 0..3  (N quarter)

    // preload scalar row/col terms and fold into accumulator init
    float s0v[8][4];
    #pragma unroll
    for (int m = 0; m < 8; ++m)
        #pragma unroll
        for (int r = 0; r < 4; ++r)
            s0v[m][r] = s0[(size_t)b * L_ + brow + wr * 128 + m * 16 + (lane >> 4) * 4 + r];
    float s1v[4];
    #pragma unroll
    for (int n = 0; n < 4; ++n)
        s1v[n] = s1[(size_t)b * L_ + bcol + wc * 64 + n * 16 + (lane & 15)];

    f32x4 acc[8][4];
    #pragma unroll
    for (int m = 0; m < 8; ++m)
        #pragma unroll
        for (int n = 0; n < 4; ++n)
            #pragma unroll
            for (int r = 0; r < 4; ++r)
                acc[m][n][r] = s0v[m][r] + s1v[n];

    // --- stage step s into buffer s%3 (2 A + 2 Q gload_lds per thread) ---
    // LDS row = 64B = 4 slots of 16B; slot' = slot ^ ((row>>1)&3)
    auto stage = [&](int s) {
        const int k0 = s * BK;
        unsigned short* ab = &As[s % 3][0];
        unsigned short* qb = &Qs[s % 3][0];
        #pragma unroll
        for (int i = 0; i < 2; ++i) {
            const int sidx = i * 512 + wave * 64 + lane;   // 0..1023
            const int row  = sidx >> 2;                    // 0..255
            const int sl   = sidx & 3;
            const int ksrc = k0 + ((sl ^ ((row >> 1) & 3)) << 3);
            const int wbase = (i * 512 + wave * 64) * 8;   // ushort idx, wave-uniform
            gload_lds16(Ab + (size_t)row * D_ + ksrc, ab + wbase);
            gload_lds16(Qb + (size_t)row * D_ + ksrc, qb + wbase);
        }
    };

    // --- compute step t from buffer t%3 (12 ds_read_b128 + 32 MFMA) ---
    auto compute = [&](int t) {
        const unsigned short* ab = &As[t % 3][0];
        const unsigned short* qb = &Qs[t % 3][0];
        bf16x8 af[8], qf[4];
        #pragma unroll
        for (int m = 0; m < 8; ++m) {
            const int row = wr * 128 + m * 16 + (lane & 15);
            const int idx = row * 32 + (((lane >> 4) ^ ((row >> 1) & 3)) << 3);
            af[m] = *(const bf16x8*)(ab + idx);
        }
        #pragma unroll
        for (int n = 0; n < 4; ++n) {
            const int row = wc * 64 + n * 16 + (lane & 15);
            const int idx = row * 32 + (((lane >> 4) ^ ((row >> 1) & 3)) << 3);
            qf[n] = *(const bf16x8*)(qb + idx);
        }
        __builtin_amdgcn_s_setprio(1);
        #pragma unroll
        for (int m = 0; m < 8; ++m)
            #pragma unroll
            for (int n = 0; n < 4; ++n)
                acc[m][n] = __builtin_amdgcn_mfma_f32_16x16x32_bf16(
                    af[m], qf[n], acc[m][n], 0, 0, 0);
        __builtin_amdgcn_s_setprio(0);
    };

    stage(0);
    stage(1);

#define STEP(T, VM) do {                                        \
        if ((T) + 2 < NSTEP) stage((T) + 2);                    \
        asm volatile("s_waitcnt vmcnt(" #VM ")" ::: "memory");  \
        __builtin_amdgcn_s_barrier();                           \
        asm volatile("" ::: "memory");                          \
        compute(T);                                             \
        asm volatile("" ::: "memory");                          \
        __builtin_amdgcn_s_barrier();                           \
        asm volatile("" ::: "memory");                          \
    } while (0)

    STEP(0, 8); STEP(1, 8); STEP(2, 8); STEP(3, 8);
    STEP(4, 8); STEP(5, 8); STEP(6, 4); STEP(7, 0);
#undef STEP

    // epilogue: accumulators already hold s0+s1; burst stores
    float* outb = out + ((size_t)b * L_ + brow) * L_ + bcol;
    #pragma unroll
    for (int m = 0; m < 8; ++m) {
        #pragma unroll
        for (int r = 0; r < 4; ++r) {
            const int row = wr * 128 + m * 16 + (lane >> 4) * 4 + r;
            float* rp = outb + (size_t)row * L_;
            #pragma unroll
            for (int n = 0; n < 4; ++n)
                rp[wc * 64 + n * 16 + (lane & 15)] = acc[m][n][r];
        }
    }
}

// ---------------- fallback (workspace too small): naive, correct, slow ------
__global__ void naive_kernel(const float* __restrict__ c, const float* __restrict__ q,
                             const float* __restrict__ cw, const float* __restrict__ qw,
                             const float* __restrict__ cqw, const float* __restrict__ bias,
                             float* __restrict__ out)
{
    const size_t total = (size_t)B_ * L_ * L_;
    for (size_t idx = (size_t)blockIdx.x * blockDim.x + threadIdx.x; idx < total;
         idx += (size_t)gridDim.x * blockDim.x) {
        const int b = (int)(idx / ((size_t)L_ * L_));
        const int rem = (int)(idx % ((size_t)L_ * L_));
        const int i = rem / L_, j = rem % L_;
        const float* ci = c + ((size_t)b * L_ + i) * D_;
        const float* cj = c + ((size_t)b * L_ + j) * D_;
        const float* qj = q + ((size_t)b * L_ + j) * D_;
        float acc = bias[0];
        for (int d = 0; d < D_; ++d)
            acc += ci[d] * cw[d] + cj[d] * qw[d] + ci[d] * cqw[d] * qj[d];
        out[idx] = acc;
    }
}

extern "C" void kernel_launch(void* const* d_in, const int* in_sizes, int n_in,
                              void* d_out, int out_size, void* d_ws, size_t ws_size,
                              hipStream_t stream) {
    const float* c    = (const float*)d_in[0];
    const float* q    = (const float*)d_in[1];
    const float* cw   = (const float*)d_in[2];
    const float* qw   = (const float*)d_in[3];
    const float* cqw  = (const float*)d_in[4];
    const float* bias = (const float*)d_in[5];
    float* out = (float*)d_out;

    const size_t bytesA = (size_t)B_ * L_ * D_ * 2;            // 8 MiB
    const size_t need   = 2 * bytesA + 2 * (size_t)B_ * L_ * 4; // ~16.1 MiB

    if (ws_size >= need) {
        unsigned short* Abf = (unsigned short*)d_ws;
        unsigned short* Qbf = (unsigned short*)((char*)d_ws + bytesA);
        float* s0 = (float*)((char*)d_ws + 2 * bytesA);
        float* s1 = s0 + (size_t)B_ * L_;
        prep_kernel<<<B_ * L_ / 4, 256, 0, stream>>>(c, q, cw, qw, cqw, bias,
                                                     Abf, Qbf, s0, s1);
        gemm_kernel<<<dim3(512), 512, 0, stream>>>(Abf, Qbf, s0, s1, out);
    } else {
        naive_kernel<<<2048, 256, 0, stream>>>(c, q, cw, qw, cqw, bias, out);
    }
}